// Round 4
// baseline (119.438 us; speedup 1.0000x reference)
//
#include <hip/hip_runtime.h>
#include <math.h>

// B=64, S=1024, D=16, L=2. Single fused kernel.
// grid = 64 batches x 8 query-chunks = 512 blocks, block = 1024 threads (16 waves).
// LDS 53 KB/block -> 2 blocks/CU co-resident (106 KB < 160 KB) -> 32 waves/CU.
// CRITICAL: VGPR must be <= 64 for 8 waves/SIMD; a 16-wave block only fits twice
// per CU at exactly <=64. Round 0's 2-key-unroll loop compiled to 64; round 3's
// 4-key unroll likely crossed it (flat result == 1 block/CU degeneracy). This
// version restores the 2-key unroll and halves live accumulator state vs round 0
// (2 queries/lane instead of 4), so VGPR <= 64 with margin.
// NOTE: plain __launch_bounds__(1024) — (1024,8) makes the compiler cap VGPRs
// at 32 and spill ~53 MB to scratch (round 1: WRITE_SIZE 4->57 MB, dur 65 us).
// wave w = key-slice ks (wave-uniform -> all LDS reads are same-address broadcast,
// conflict-free). Each lane handles 2 queries {lane, lane+64} over 64 keys.
// No-max softmax (|score| <~ 1.5, exp2 cannot overflow); 0.25*log2(e) folded
// into the Q projection so the inner loop uses raw v_exp_f32.

__device__ __forceinline__ void load_row16(const float* __restrict__ p, float* dst) {
    const float4* p4 = (const float4*)p;
    float4 r0 = p4[0], r1 = p4[1], r2 = p4[2], r3 = p4[3];
    dst[0]=r0.x;  dst[1]=r0.y;  dst[2]=r0.z;  dst[3]=r0.w;
    dst[4]=r1.x;  dst[5]=r1.y;  dst[6]=r1.z;  dst[7]=r1.w;
    dst[8]=r2.x;  dst[9]=r2.y;  dst[10]=r2.z; dst[11]=r2.w;
    dst[12]=r3.x; dst[13]=r3.y; dst[14]=r3.z; dst[15]=r3.w;
}

__device__ __forceinline__ void matvec16(const float* v, const float* W,
                                         const float* __restrict__ bias, float* y) {
#pragma unroll
    for (int j = 0; j < 16; ++j) y[j] = bias[j];
#pragma unroll
    for (int i = 0; i < 16; ++i) {
        float vi = v[i];
#pragma unroll
        for (int j = 0; j < 16; ++j) y[j] = fmaf(vi, W[i*16 + j], y[j]);
    }
}

__device__ __forceinline__ void layernorm16(float* h, const float* __restrict__ g,
                                            const float* __restrict__ bb) {
    float mu = 0.f;
#pragma unroll
    for (int j = 0; j < 16; ++j) mu += h[j];
    mu *= 0.0625f;
    float var = 0.f;
#pragma unroll
    for (int j = 0; j < 16; ++j) { float d = h[j] - mu; var = fmaf(d, d, var); }
    var *= 0.0625f;
    float rs = rsqrtf(var + 1e-5f);
#pragma unroll
    for (int j = 0; j < 16; ++j) h[j] = (h[j] - mu) * rs * g[j] + bb[j];
}

__global__ __launch_bounds__(1024)
void fused_encoder(const float* __restrict__ x,
                   const float* __restrict__ Wq, const float* __restrict__ bq,
                   const float* __restrict__ Wk, const float* __restrict__ bk,
                   const float* __restrict__ Wv, const float* __restrict__ bv,
                   const float* __restrict__ Wu, const float* __restrict__ bu,
                   const float* __restrict__ ln_g, const float* __restrict__ ln_b,
                   const float* __restrict__ W1, const float* __restrict__ b1,
                   const float* __restrict__ W2, const float* __restrict__ b2,
                   const float* __restrict__ W3, const float* __restrict__ b3,
                   const float* __restrict__ Wo, const float* __restrict__ bo,
                   float* __restrict__ out)
{
    __shared__ float4 skv[1024];       // (k0,k1,v0,v1) per key row, 16 KB
    __shared__ float2 sq[128];         // pre-scaled (q0,q1) per query, 1 KB
    __shared__ float  sW[1024];        // W1|W2|W3|Wo, 4 KB
    __shared__ float4 sp[16][128];     // partial (L, A0, A1, -) per slice, 32 KB

    const int tid  = threadIdx.x;
    const int b    = blockIdx.x >> 3;
    const int chunk= blockIdx.x & 7;   // 8 chunks x 128 queries
    const int lane = tid & 63;
    const int ks   = tid >> 6;         // wave id == key-slice, wave-uniform

    const float* xb = x + (size_t)b * 1024 * 16;

    // ---- Phase 1a: thread tid computes K/V row `tid` into LDS
    {
        float xr[16];
        load_row16(xb + tid * 16, xr);
        float k0 = bk[0], k1 = bk[1], v0 = bv[0], v1 = bv[1];
#pragma unroll
        for (int i = 0; i < 16; ++i) {
            k0 = fmaf(xr[i], Wk[2*i],   k0);
            k1 = fmaf(xr[i], Wk[2*i+1], k1);
            v0 = fmaf(xr[i], Wv[2*i],   v0);
            v1 = fmaf(xr[i], Wv[2*i+1], v1);
        }
        skv[tid] = make_float4(k0, k1, v0, v1);
    }

    // ---- Phase 1b: stage epilogue weights
    {
        const float* Ws = (tid < 256) ? W1 : (tid < 512) ? W2
                        : (tid < 768) ? W3 : Wo;
        sW[tid] = Ws[tid & 255];
    }

    // ---- Phase 1c: Q projection once per query (threads 0..127).
    //      Fold softmax scale 1/4 AND log2(e) so the loop uses exp2 directly.
    if (tid < 128) {
        const int qi = chunk * 128 + tid;
        float xr[16];
        load_row16(xb + qi * 16, xr);
        float q0 = bq[0], q1 = bq[1];
#pragma unroll
        for (int i = 0; i < 16; ++i) {
            q0 = fmaf(xr[i], Wq[2*i],   q0);
            q1 = fmaf(xr[i], Wq[2*i+1], q1);
        }
        const float SC = 0.25f * 1.44269504088896340736f;
        sq[tid] = make_float2(q0 * SC, q1 * SC);
    }
    __syncthreads();

    // ---- Phase 2: each lane: 2 queries x 64 keys; one broadcast b128 read
    //      feeds 10 FMA + 2 v_exp. 2-key unroll keeps live state minimal
    //      (VGPR <= 64 is the 2-blocks/CU requirement).
    float q0[2], q1[2], L[2], A0[2], A1[2];
#pragma unroll
    for (int j = 0; j < 2; ++j) {
        float2 qq = sq[lane + 64*j];
        q0[j] = qq.x; q1[j] = qq.y;
        L[j] = 0.f; A0[j] = 0.f; A1[j] = 0.f;
    }
    const int kbase = ks * 64;
    for (int t = 0; t < 64; t += 2) {
        const float4 c0 = skv[kbase + t];
        const float4 c1 = skv[kbase + t + 1];
#pragma unroll
        for (int j = 0; j < 2; ++j) {
            float p0 = __builtin_amdgcn_exp2f(fmaf(q1[j], c0.y, q0[j] * c0.x));
            float p1 = __builtin_amdgcn_exp2f(fmaf(q1[j], c1.y, q0[j] * c1.x));
            L[j] += p0;  A0[j] = fmaf(p0, c0.z, A0[j]);  A1[j] = fmaf(p0, c0.w, A1[j]);
            L[j] += p1;  A0[j] = fmaf(p1, c1.z, A0[j]);  A1[j] = fmaf(p1, c1.w, A1[j]);
        }
    }
#pragma unroll
    for (int j = 0; j < 2; ++j) {
        const int q = lane + 64*j;                  // lanes consecutive -> no conflict
        sp[ks][q] = make_float4(L[j], A0[j], A1[j], 0.f);
    }
    __syncthreads();

    // ---- Phase 3: threads 0..127 reduce 16 slices (b128 reads) + per-row epilogue
    if (tid < 128) {
        float l = 0.f, a0 = 0.f, a1 = 0.f;
#pragma unroll
        for (int s = 0; s < 16; ++s) {
            float4 p = sp[s][tid];
            l += p.x;  a0 += p.y;  a1 += p.z;
        }
        const float rl = 1.0f / l;
        const float c0 = a0 * rl, c1 = a1 * rl;

        const int qi = chunk * 128 + tid;
        float xq[16];
        load_row16(xb + qi * 16, xq);               // L1/L2 hit (read in phase 1c)

        float h[16];
#pragma unroll
        for (int j = 0; j < 16; ++j)
            h[j] = fmaf(c0, Wu[j], fmaf(c1, Wu[16 + j], bu[j])) + xq[j];

        layernorm16(h, ln_g, ln_b);

        float t1[16], t2[16], t3[16];
        matvec16(h,  sW,       b1, t1);
        matvec16(t1, sW + 256, b2, t2);
        matvec16(t2, sW + 512, b3, t3);
#pragma unroll
        for (int j = 0; j < 16; ++j) t3[j] += h[j];

        layernorm16(t3, ln_g, ln_b);

        float o[16];
        matvec16(t3, sW + 768, bo, o);

        float4* orow = (float4*)(out + ((size_t)b * 1024 + qi) * 16);
        orow[0] = make_float4(o[0],  o[1],  o[2],  o[3]);
        orow[1] = make_float4(o[4],  o[5],  o[6],  o[7]);
        orow[2] = make_float4(o[8],  o[9],  o[10], o[11]);
        orow[3] = make_float4(o[12], o[13], o[14], o[15]);
    }
}

extern "C" void kernel_launch(void* const* d_in, const int* in_sizes, int n_in,
                              void* d_out, int out_size, void* d_ws, size_t ws_size,
                              hipStream_t stream) {
    const float* x    = (const float*)d_in[0];
    const float* Wq   = (const float*)d_in[1];
    const float* bq   = (const float*)d_in[2];
    const float* Wk   = (const float*)d_in[3];
    const float* bk   = (const float*)d_in[4];
    const float* Wv   = (const float*)d_in[5];
    const float* bv   = (const float*)d_in[6];
    const float* Wu   = (const float*)d_in[7];
    const float* bu   = (const float*)d_in[8];
    const float* ln_g = (const float*)d_in[9];
    const float* ln_b = (const float*)d_in[10];
    const float* W1   = (const float*)d_in[11];
    const float* b1   = (const float*)d_in[12];
    const float* W2   = (const float*)d_in[13];
    const float* b2   = (const float*)d_in[14];
    const float* W3   = (const float*)d_in[15];
    const float* b3   = (const float*)d_in[16];
    const float* Wo   = (const float*)d_in[17];
    const float* bo   = (const float*)d_in[18];
    float* out = (float*)d_out;

    hipLaunchKernelGGL(fused_encoder, dim3(512), dim3(1024), 0, stream,
                       x, Wq, bq, Wk, bk, Wv, bv, Wu, bu, ln_g, ln_b,
                       W1, b1, W2, b2, W3, b3, Wo, bo, out);
}

// Round 5
// 117.533 us; speedup vs baseline: 1.0162x; 1.0162x over previous
//
#include <hip/hip_runtime.h>
#include <math.h>

// B=64, S=1024, D=16, L=2. Single fused kernel.
// grid = 64 batches x 8 query-chunks = 512 blocks, block = 512 threads (8 waves).
// LDS 37 KB/block -> 4 blocks/CU co-resident (148 KB < 160 KB). Four INDEPENDENT
// blocks per CU are phase-staggered (separate barriers), which breaks the
// lockstep-convoy stall pattern of one big 16-wave block (rounds 0-4: all waves
// of a block hit the same lgkmcnt windows simultaneously, so same-block TLP
// hides nothing - dur stayed ~40 us regardless of waves/CU).
// wave w = 128-key slice (wave-uniform -> LDS reads are same-address broadcast,
// conflict-free). Each lane: 2 queries {lane, lane+64} x 128 keys, with an
// explicit 2-key register prefetch so each wave's own compute (~150 cy/iter)
// covers the ~120 cy LDS latency even without inter-wave overlap.
// VGPR must stay <= 64 for 8 waves/SIMD (plain __launch_bounds__; the (.,8)
// hint forces 32 VGPR + 53 MB scratch spill, round 1).
// No-max softmax (|score| <~ 1.5, exp2 cannot overflow); 0.25*log2(e) folded
// into the Q projection so the inner loop uses raw v_exp_f32.

__device__ __forceinline__ void load_row16(const float* __restrict__ p, float* dst) {
    const float4* p4 = (const float4*)p;
    float4 r0 = p4[0], r1 = p4[1], r2 = p4[2], r3 = p4[3];
    dst[0]=r0.x;  dst[1]=r0.y;  dst[2]=r0.z;  dst[3]=r0.w;
    dst[4]=r1.x;  dst[5]=r1.y;  dst[6]=r1.z;  dst[7]=r1.w;
    dst[8]=r2.x;  dst[9]=r2.y;  dst[10]=r2.z; dst[11]=r2.w;
    dst[12]=r3.x; dst[13]=r3.y; dst[14]=r3.z; dst[15]=r3.w;
}

__device__ __forceinline__ void matvec16(const float* v, const float* W,
                                         const float* __restrict__ bias, float* y) {
#pragma unroll
    for (int j = 0; j < 16; ++j) y[j] = bias[j];
#pragma unroll
    for (int i = 0; i < 16; ++i) {
        float vi = v[i];
#pragma unroll
        for (int j = 0; j < 16; ++j) y[j] = fmaf(vi, W[i*16 + j], y[j]);
    }
}

__device__ __forceinline__ void layernorm16(float* h, const float* __restrict__ g,
                                            const float* __restrict__ bb) {
    float mu = 0.f;
#pragma unroll
    for (int j = 0; j < 16; ++j) mu += h[j];
    mu *= 0.0625f;
    float var = 0.f;
#pragma unroll
    for (int j = 0; j < 16; ++j) { float d = h[j] - mu; var = fmaf(d, d, var); }
    var *= 0.0625f;
    float rs = rsqrtf(var + 1e-5f);
#pragma unroll
    for (int j = 0; j < 16; ++j) h[j] = (h[j] - mu) * rs * g[j] + bb[j];
}

__global__ __launch_bounds__(512)
void fused_encoder(const float* __restrict__ x,
                   const float* __restrict__ Wq, const float* __restrict__ bq,
                   const float* __restrict__ Wk, const float* __restrict__ bk,
                   const float* __restrict__ Wv, const float* __restrict__ bv,
                   const float* __restrict__ Wu, const float* __restrict__ bu,
                   const float* __restrict__ ln_g, const float* __restrict__ ln_b,
                   const float* __restrict__ W1, const float* __restrict__ b1,
                   const float* __restrict__ W2, const float* __restrict__ b2,
                   const float* __restrict__ W3, const float* __restrict__ b3,
                   const float* __restrict__ Wo, const float* __restrict__ bo,
                   float* __restrict__ out)
{
    __shared__ float4 skv[1024];       // (k0,k1,v0,v1) per key row, 16 KB
    __shared__ float2 sq[128];         // pre-scaled (q0,q1) per query, 1 KB
    __shared__ float  sW[1024];        // W1|W2|W3|Wo, 4 KB
    __shared__ float4 sp[8][128];      // partial (L, A0, A1, -) per slice, 16 KB

    const int tid  = threadIdx.x;
    const int b    = blockIdx.x >> 3;
    const int chunk= blockIdx.x & 7;   // 8 chunks x 128 queries
    const int lane = tid & 63;
    const int ks   = tid >> 6;         // wave id == 128-key slice, wave-uniform

    const float* xb = x + (size_t)b * 1024 * 16;

    // ---- Phase 1a: 512 threads compute 1024 K/V rows into LDS (2 rows each)
#pragma unroll
    for (int r = tid; r < 1024; r += 512) {
        float xr[16];
        load_row16(xb + r * 16, xr);
        float k0 = bk[0], k1 = bk[1], v0 = bv[0], v1 = bv[1];
#pragma unroll
        for (int i = 0; i < 16; ++i) {
            k0 = fmaf(xr[i], Wk[2*i],   k0);
            k1 = fmaf(xr[i], Wk[2*i+1], k1);
            v0 = fmaf(xr[i], Wv[2*i],   v0);
            v1 = fmaf(xr[i], Wv[2*i+1], v1);
        }
        skv[r] = make_float4(k0, k1, v0, v1);
    }

    // ---- Phase 1b: stage epilogue weights (2 each)
#pragma unroll
    for (int i = tid; i < 1024; i += 512) {
        const float* Ws = (i < 256) ? W1 : (i < 512) ? W2
                        : (i < 768) ? W3 : Wo;
        sW[i] = Ws[i & 255];
    }

    // ---- Phase 1c: Q projection once per query (threads 0..127).
    //      Fold softmax scale 1/4 AND log2(e) so the loop uses exp2 directly.
    if (tid < 128) {
        const int qi = chunk * 128 + tid;
        float xr[16];
        load_row16(xb + qi * 16, xr);
        float q0 = bq[0], q1 = bq[1];
#pragma unroll
        for (int i = 0; i < 16; ++i) {
            q0 = fmaf(xr[i], Wq[2*i],   q0);
            q1 = fmaf(xr[i], Wq[2*i+1], q1);
        }
        const float SC = 0.25f * 1.44269504088896340736f;
        sq[tid] = make_float2(q0 * SC, q1 * SC);
    }
    __syncthreads();

    // ---- Phase 2: each lane: 2 queries x 128 keys, 2-key register prefetch.
    float q0[2], q1[2], L[2], A0[2], A1[2];
#pragma unroll
    for (int j = 0; j < 2; ++j) {
        float2 qq = sq[lane + 64*j];
        q0[j] = qq.x; q1[j] = qq.y;
        L[j] = 0.f; A0[j] = 0.f; A1[j] = 0.f;
    }
    const int kbase = ks * 128;
    float4 c0 = skv[kbase + 0];
    float4 c1 = skv[kbase + 1];
#pragma unroll 4
    for (int t = 0; t < 126; t += 2) {
        float4 n0 = skv[kbase + t + 2];      // issue next loads BEFORE compute
        float4 n1 = skv[kbase + t + 3];
#pragma unroll
        for (int j = 0; j < 2; ++j) {
            float p0 = __builtin_amdgcn_exp2f(fmaf(q1[j], c0.y, q0[j] * c0.x));
            float p1 = __builtin_amdgcn_exp2f(fmaf(q1[j], c1.y, q0[j] * c1.x));
            L[j] += p0;  A0[j] = fmaf(p0, c0.z, A0[j]);  A1[j] = fmaf(p0, c0.w, A1[j]);
            L[j] += p1;  A0[j] = fmaf(p1, c1.z, A0[j]);  A1[j] = fmaf(p1, c1.w, A1[j]);
        }
        c0 = n0; c1 = n1;
    }
#pragma unroll
    for (int j = 0; j < 2; ++j) {            // tail pair (t = 126,127)
        float p0 = __builtin_amdgcn_exp2f(fmaf(q1[j], c0.y, q0[j] * c0.x));
        float p1 = __builtin_amdgcn_exp2f(fmaf(q1[j], c1.y, q0[j] * c1.x));
        L[j] += p0;  A0[j] = fmaf(p0, c0.z, A0[j]);  A1[j] = fmaf(p0, c0.w, A1[j]);
        L[j] += p1;  A0[j] = fmaf(p1, c1.z, A0[j]);  A1[j] = fmaf(p1, c1.w, A1[j]);
    }
#pragma unroll
    for (int j = 0; j < 2; ++j) {
        const int q = lane + 64*j;           // lanes consecutive -> no conflict
        sp[ks][q] = make_float4(L[j], A0[j], A1[j], 0.f);
    }
    __syncthreads();

    // ---- Phase 3: threads 0..127 reduce 8 slices (b128 reads) + per-row epilogue
    if (tid < 128) {
        float l = 0.f, a0 = 0.f, a1 = 0.f;
#pragma unroll
        for (int s = 0; s < 8; ++s) {
            float4 p = sp[s][tid];
            l += p.x;  a0 += p.y;  a1 += p.z;
        }
        const float rl = 1.0f / l;
        const float c0 = a0 * rl, c1 = a1 * rl;

        const int qi = chunk * 128 + tid;
        float xq[16];
        load_row16(xb + qi * 16, xq);        // L1/L2 hit (read in phase 1c)

        float h[16];
#pragma unroll
        for (int j = 0; j < 16; ++j)
            h[j] = fmaf(c0, Wu[j], fmaf(c1, Wu[16 + j], bu[j])) + xq[j];

        layernorm16(h, ln_g, ln_b);

        float t1[16], t2[16], t3[16];
        matvec16(h,  sW,       b1, t1);
        matvec16(t1, sW + 256, b2, t2);
        matvec16(t2, sW + 512, b3, t3);
#pragma unroll
        for (int j = 0; j < 16; ++j) t3[j] += h[j];

        layernorm16(t3, ln_g, ln_b);

        float o[16];
        matvec16(t3, sW + 768, bo, o);

        float4* orow = (float4*)(out + ((size_t)b * 1024 + qi) * 16);
        orow[0] = make_float4(o[0],  o[1],  o[2],  o[3]);
        orow[1] = make_float4(o[4],  o[5],  o[6],  o[7]);
        orow[2] = make_float4(o[8],  o[9],  o[10], o[11]);
        orow[3] = make_float4(o[12], o[13], o[14], o[15]);
    }
}

extern "C" void kernel_launch(void* const* d_in, const int* in_sizes, int n_in,
                              void* d_out, int out_size, void* d_ws, size_t ws_size,
                              hipStream_t stream) {
    const float* x    = (const float*)d_in[0];
    const float* Wq   = (const float*)d_in[1];
    const float* bq   = (const float*)d_in[2];
    const float* Wk   = (const float*)d_in[3];
    const float* bk   = (const float*)d_in[4];
    const float* Wv   = (const float*)d_in[5];
    const float* bv   = (const float*)d_in[6];
    const float* Wu   = (const float*)d_in[7];
    const float* bu   = (const float*)d_in[8];
    const float* ln_g = (const float*)d_in[9];
    const float* ln_b = (const float*)d_in[10];
    const float* W1   = (const float*)d_in[11];
    const float* b1   = (const float*)d_in[12];
    const float* W2   = (const float*)d_in[13];
    const float* b2   = (const float*)d_in[14];
    const float* W3   = (const float*)d_in[15];
    const float* b3   = (const float*)d_in[16];
    const float* Wo   = (const float*)d_in[17];
    const float* bo   = (const float*)d_in[18];
    float* out = (float*)d_out;

    hipLaunchKernelGGL(fused_encoder, dim3(512), dim3(512), 0, stream,
                       x, Wq, bq, Wk, bk, Wv, bv, Wu, bu, ln_g, ln_b,
                       W1, b1, W2, b2, W3, b3, Wo, bo, out);
}